// Round 1
// baseline (5288.672 us; speedup 1.0000x reference)
//
#include <hip/hip_runtime.h>
#include <math.h>

#define N   4096
#define NO  8192
#define BM  128
#define BN  128
#define BK  16
#define APAD 4

#ifndef M_PI
#define M_PI 3.14159265358979323846
#endif

// ws layout: w[0..N-1] = interpolation weights (float), w[N] = sign-sum S accumulator.

__global__ void init_weights_kernel(float* w) {
    int m = blockIdx.x * blockDim.x + threadIdx.x;
    if (m < N) {
        double ang = M_PI * (2.0 * (double)m + 1.0) / (2.0 * (double)N);
        double v = (cos(ang) / sin(ang)) / (double)N;
        w[m] = (m & 1) ? (float)(-v) : (float)v;
    }
    if (blockIdx.x == 0 && threadIdx.x == 0) w[N] = 0.0f;
}

__global__ void reduce_sign_kernel(const float* __restrict__ x, float* S) {
    const size_t NN = (size_t)N * N;
    float acc = 0.0f;
    for (size_t idx = (size_t)blockIdx.x * blockDim.x + threadIdx.x; idx < NN;
         idx += (size_t)gridDim.x * blockDim.x) {
        int st = (int)((idx >> 12) + (idx & (N - 1)));
        float v = x[idx];
        acc += (st & 1) ? -v : v;
    }
    #pragma unroll
    for (int off = 32; off > 0; off >>= 1) acc += __shfl_down(acc, off, 64);
    __shared__ float wsum[4];
    int lane = threadIdx.x & 63;
    int wv   = threadIdx.x >> 6;
    if (lane == 0) wsum[wv] = acc;
    __syncthreads();
    if (threadIdx.x == 0) atomicAdd(S, wsum[0] + wsum[1] + wsum[2] + wsum[3]);
}

// Horizontal pass: Z[s][j] = sum_t x[s][t] * kw[(j - t) mod N]
// Writes even output rows: out[2s][2j] = x[s][j], out[2s][2j+1] = Z[s][j]
__global__ __launch_bounds__(256) void hpass_kernel(const float* __restrict__ x,
                                                    const float* __restrict__ w,
                                                    float* __restrict__ out) {
    const int s0 = blockIdx.y * BM;
    const int j0 = blockIdx.x * BN;
    __shared__ float Asub[BK][BM + APAD];          // Asub[kk][ss] = x[s0+ss][t0+kk]
    __shared__ float kseg[BN + BK + 1];            // 143 used

    const int tid = threadIdx.x;
    const int tx = tid & 15;
    const int ty = tid >> 4;

    float acc[8][8];
    #pragma unroll
    for (int i = 0; i < 8; ++i)
        #pragma unroll
        for (int j = 0; j < 8; ++j) acc[i][j] = 0.0f;

    for (int t0 = 0; t0 < N; t0 += BK) {
        // Stage A tile (transposed): 128 rows x 16 cols
        #pragma unroll
        for (int r = 0; r < 8; ++r) {
            int ss = (tid >> 4) + (r << 4);
            Asub[tid & 15][ss] = x[(size_t)(s0 + ss) * N + (size_t)(t0 + (tid & 15))];
        }
        // Stage Toeplitz kernel segment: kseg[i] = kw[(j0 - t0 - 15 + i) mod N]
        for (int i = tid; i < BN + BK - 1; i += 256)
            kseg[i] = w[(j0 - t0 - (BK - 1) + i) & (N - 1)];
        __syncthreads();

        #pragma unroll
        for (int kk = 0; kk < BK; ++kk) {
            float a[8], b[8];
            #pragma unroll
            for (int r = 0; r < 4; ++r) {
                a[r]     = Asub[kk][ty * 4 + r];
                a[4 + r] = Asub[kk][64 + ty * 4 + r];
                b[r]     = kseg[tx * 4 + r - kk + (BK - 1)];
                b[4 + r] = kseg[64 + tx * 4 + r - kk + (BK - 1)];
            }
            #pragma unroll
            for (int i = 0; i < 8; ++i)
                #pragma unroll
                for (int j = 0; j < 8; ++j)
                    acc[i][j] += a[i] * b[j];
        }
        __syncthreads();
    }

    // Epilogue: write even rows as (x, Z) pairs
    #pragma unroll
    for (int i = 0; i < 8; ++i) {
        int ss = (i < 4) ? (ty * 4 + i) : (64 + ty * 4 + (i - 4));
        int s = s0 + ss;
        #pragma unroll
        for (int j = 0; j < 8; ++j) {
            int jj = (j < 4) ? (tx * 4 + j) : (64 + tx * 4 + (j - 4));
            int jc = j0 + jj;
            float xv = x[(size_t)s * N + jc];
            float2 v = make_float2(xv, acc[i][j]);
            *(float2*)(&out[(size_t)(2 * s) * NO + (size_t)(2 * jc)]) = v;
        }
    }
}

// Vertical pass: y[2i+1][b] = sum_s E[s][b] * kh[(i - s) mod N]  (E = even rows of out)
//                minus (for odd b) (-1)^{i+j} * S/(N*N)
__global__ __launch_bounds__(256) void vpass_kernel(const float* E,
                                                    const float* __restrict__ w,
                                                    float* out) {
    const int i0 = blockIdx.y * BM;
    const int b0 = blockIdx.x * BN;
    __shared__ float Esub[BK][BN + APAD];
    __shared__ float kseg[BM + BK + 1];

    const int tid = threadIdx.x;
    const int tx = tid & 15;
    const int ty = tid >> 4;

    float acc[8][8];
    #pragma unroll
    for (int i = 0; i < 8; ++i)
        #pragma unroll
        for (int j = 0; j < 8; ++j) acc[i][j] = 0.0f;

    for (int s0 = 0; s0 < N; s0 += BK) {
        // Stage E tile: rows s0..s0+15 (even out rows), cols b0..b0+127
        #pragma unroll
        for (int r = 0; r < 8; ++r) {
            int row = (tid >> 7) + 2 * r;
            int col = tid & 127;
            Esub[row][col] = E[(size_t)(2 * (s0 + row)) * NO + (size_t)(b0 + col)];
        }
        // Stage kernel segment: kseg[idx] = kh[(i0 - s0 - 15 + idx) mod N]
        for (int i = tid; i < BM + BK - 1; i += 256)
            kseg[i] = w[(i0 - s0 - (BK - 1) + i) & (N - 1)];
        __syncthreads();

        #pragma unroll
        for (int kk = 0; kk < BK; ++kk) {
            float a[8], b[8];
            #pragma unroll
            for (int r = 0; r < 4; ++r) {
                a[r]     = kseg[ty * 4 + r - kk + (BK - 1)];
                a[4 + r] = kseg[64 + ty * 4 + r - kk + (BK - 1)];
                b[r]     = Esub[kk][tx * 4 + r];
                b[4 + r] = Esub[kk][64 + tx * 4 + r];
            }
            #pragma unroll
            for (int i = 0; i < 8; ++i)
                #pragma unroll
                for (int j = 0; j < 8; ++j)
                    acc[i][j] += a[i] * b[j];
        }
        __syncthreads();
    }

    const float Sval = w[N] * (1.0f / ((float)N * (float)N));

    #pragma unroll
    for (int i = 0; i < 8; ++i) {
        int ii = (i < 4) ? (ty * 4 + i) : (64 + ty * 4 + (i - 4));
        int irow = i0 + ii;
        #pragma unroll
        for (int j = 0; j < 8; ++j) {
            int jj = (j < 4) ? (tx * 4 + j) : (64 + tx * 4 + (j - 4));
            int b = b0 + jj;
            float v = acc[i][j];
            if (b & 1) {
                int jdx = (b - 1) >> 1;
                v -= (((irow + jdx) & 1) ? -Sval : Sval);
            }
            out[(size_t)(2 * irow + 1) * NO + (size_t)b] = v;
        }
    }
}

extern "C" void kernel_launch(void* const* d_in, const int* in_sizes, int n_in,
                              void* d_out, int out_size, void* d_ws, size_t ws_size,
                              hipStream_t stream) {
    const float* x = (const float*)d_in[0];
    float* out = (float*)d_out;
    float* w = (float*)d_ws;   // needs (N+1) floats = 16.4 KB

    init_weights_kernel<<<(N + 255) / 256, 256, 0, stream>>>(w);
    reduce_sign_kernel<<<1024, 256, 0, stream>>>(x, w + N);

    dim3 hgrid(N / BN, N / BM);
    hpass_kernel<<<hgrid, 256, 0, stream>>>(x, w, out);

    dim3 vgrid(NO / BN, N / BM);
    vpass_kernel<<<vgrid, 256, 0, stream>>>(out, w, out);
}